// Round 1
// baseline (5822.310 us; speedup 1.0000x reference)
//
#include <hip/hip_runtime.h>

// LSTM stack: B=256 batch rows (one block each), T=1024 steps.
// Layer l kernel: thread j owns gate column j (g = [i|f|cbar|o], 4*U cols),
// holds Wx[:,j] (DIN regs) + Wh[:,j] (U regs) in VGPRs. h, x_t in LDS
// (wave-uniform broadcast reads). Threads 0..U-1 additionally own the
// c/h state update for unit tid.

#define BATCH 256
#define TSTEPS 1024

__device__ __forceinline__ float sigm(float x) {
    return 1.0f / (1.0f + __expf(-x));
}

__device__ __forceinline__ float tanh_fast(float x) {
    // tanh(x) = sign(x)*(1 - 2/(exp(2|x|)+1)); exp overflow -> +/-1, correct.
    float ax = fabsf(x);
    float e = __expf(2.0f * ax);
    float r = 1.0f - 2.0f / (e + 1.0f);
    return copysignf(r, x);
}

template<int DIN, int U, int BLOCK, bool LAST>
__global__ __launch_bounds__(BLOCK, 2)
void lstm_layer_kernel(const float* __restrict__ xin,   // [B, T, DIN]
                       const float* __restrict__ Wx,    // [DIN, 4U]
                       const float* __restrict__ Wh,    // [U, 4U]
                       const float* __restrict__ bias,  // [4U]
                       float* __restrict__ xout,        // [B, T, U] (unused if LAST)
                       const float* __restrict__ Wout,  // [U] (LAST only)
                       const float* __restrict__ bout,  // [1] (LAST only)
                       float* __restrict__ dout)        // [B] (LAST only)
{
    constexpr int G    = 4 * U;
    constexpr int DINP = (DIN + 3) & ~3;   // pad to float4
    constexpr int UP   = (U + 3) & ~3;

    const int b   = blockIdx.x;
    const int tid = threadIdx.x;

    __shared__ __align__(16) float s_x[DINP];
    __shared__ __align__(16) float s_h[UP];
    __shared__ float s_g[G];

    // --- load this column's weights into registers (coalesced across lanes) ---
    float wx[DINP];
    float wh[UP];
    float bj = 0.0f;
    if (tid < G) {
#pragma unroll
        for (int k = 0; k < DIN; ++k) wx[k] = Wx[k * G + tid];
#pragma unroll
        for (int k = DIN; k < DINP; ++k) wx[k] = 0.0f;
#pragma unroll
        for (int k = 0; k < U; ++k) wh[k] = Wh[k * G + tid];
#pragma unroll
        for (int k = U; k < UP; ++k) wh[k] = 0.0f;
        bj = bias[tid];
    }

    const float* xrow = xin + (size_t)b * TSTEPS * DIN;

    float c = 0.0f;                        // cell state for unit `tid` (tid < U)
    if (tid < DINP) s_x[tid] = (tid < DIN) ? xrow[tid] : 0.0f;
    if (tid < UP)   s_h[tid] = 0.0f;
    __syncthreads();

    for (int t = 0; t < TSTEPS; ++t) {
        // prefetch next timestep's input (latency hides under the FMA phase)
        float xn = 0.0f;
        if (tid < DIN) {
            int tn = (t + 1 < TSTEPS) ? (t + 1) : t;
            xn = xrow[(size_t)tn * DIN + tid];
        }

        if (tid < G) {
            float a0 = bj, a1 = 0.0f, a2 = 0.0f, a3 = 0.0f;
#pragma unroll
            for (int k = 0; k < DINP; k += 4) {
                float4 v = *(const float4*)(s_x + k);   // broadcast ds_read_b128
                a0 = fmaf(v.x, wx[k + 0], a0);
                a1 = fmaf(v.y, wx[k + 1], a1);
                a2 = fmaf(v.z, wx[k + 2], a2);
                a3 = fmaf(v.w, wx[k + 3], a3);
            }
#pragma unroll
            for (int k = 0; k < UP; k += 4) {
                float4 v = *(const float4*)(s_h + k);
                a0 = fmaf(v.x, wh[k + 0], a0);
                a1 = fmaf(v.y, wh[k + 1], a1);
                a2 = fmaf(v.z, wh[k + 2], a2);
                a3 = fmaf(v.w, wh[k + 3], a3);
            }
            s_g[tid] = (a0 + a1) + (a2 + a3);
        }
        __syncthreads();   // g complete; everyone done reading s_x / s_h

        if (tid < U) {
            float gi = s_g[tid];
            float gf = s_g[U + tid];
            float gc = s_g[2 * U + tid];
            float go = s_g[3 * U + tid];
            float fi = sigm(gi);
            float ff = sigm(gf);
            float fo = sigm(go);
            c = ff * c + fi * tanh_fast(gc);
            float h = fo * tanh_fast(c);
            s_h[tid] = h;
            if (!LAST) xout[((size_t)b * TSTEPS + t) * U + tid] = h;
        }
        if (tid < DIN) s_x[tid] = xn;      // safe: all reads of s_x done at barrier above
        __syncthreads();                   // h, x ready for next step
    }

    if (LAST) {
        if (tid == 0) {
            float acc = bout[0];
#pragma unroll
            for (int k = 0; k < U; ++k) acc = fmaf(s_h[k], Wout[k], acc);
            dout[b] = acc;
        }
    }
}

extern "C" void kernel_launch(void* const* d_in, const int* in_sizes, int n_in,
                              void* d_out, int out_size, void* d_ws, size_t ws_size,
                              hipStream_t stream)
{
    const float* seq  = (const float*)d_in[0];
    const float* Wx0  = (const float*)d_in[1];
    const float* Wh0  = (const float*)d_in[2];
    const float* b0   = (const float*)d_in[3];
    const float* Wx1  = (const float*)d_in[4];
    const float* Wh1  = (const float*)d_in[5];
    const float* b1   = (const float*)d_in[6];
    const float* Wx2  = (const float*)d_in[7];
    const float* Wh2  = (const float*)d_in[8];
    const float* b2   = (const float*)d_in[9];
    const float* Wx3  = (const float*)d_in[10];
    const float* Wh3  = (const float*)d_in[11];
    const float* b3   = (const float*)d_in[12];
    const float* Wout = (const float*)d_in[13];
    const float* bout = (const float*)d_in[14];
    float* out = (float*)d_out;

    float* ws = (float*)d_ws;
    float* X1 = ws;                         // [256,1024,100] = 104,857,600 B
    float* X2 = ws + (size_t)BATCH * TSTEPS * 100;  // [256,1024,80] = 83,886,080 B
    float* X3 = ws;                         // [256,1024,50] reuses X1's region

    dim3 grid(BATCH);

    lstm_layer_kernel<64, 100, 448, false><<<grid, 448, 0, stream>>>(
        seq, Wx0, Wh0, b0, X1, nullptr, nullptr, nullptr);
    lstm_layer_kernel<100, 80, 320, false><<<grid, 320, 0, stream>>>(
        X1, Wx1, Wh1, b1, X2, nullptr, nullptr, nullptr);
    lstm_layer_kernel<80, 50, 256, false><<<grid, 256, 0, stream>>>(
        X2, Wx2, Wh2, b2, X3, nullptr, nullptr, nullptr);
    lstm_layer_kernel<50, 30, 128, true><<<grid, 128, 0, stream>>>(
        X3, Wx3, Wh3, b3, nullptr, Wout, bout, out);
}